// Round 22
// baseline (211.945 us; speedup 1.0000x reference)
//
#include <hip/hip_runtime.h>

// VectorQuantizer on MI355X (gfx950) — BARRIER-FREE private-dbuf MFMA argmin.
// R22: 256 thr = 4 waves, 128 pts/block.  Wave w owns pts [w*32..+32) x ALL
// 512 codes in 32 PRIVATE 16-code chunks (8 KB/wave, dbuf'd): the main loop
// has ZERO barriers and ZERO cross-wave deps — each wave free-runs on its own
// counted vmcnt(4).  LDS = 32 KiB exactly -> 5 blocks/CU = 20 waves (vs 16).
// A-frags (hi+lo) hoisted to regs; en_pre[32] preloaded.  Epilogue: two
// 64-row LDS-transpose half-passes.  Loss: per-wave scalar partials (Sum s +
// Sum xnorm).  Hist: direct global atomics.  f64 refine (fused w/ finalize)
// patches near-ties.
//
// Distance core: s = ||e||^2 - 2 x.e.  E pre-scaled by 2048, f16 hi/lo split,
// PRE-SWIZZLED in ws (per-lane gld16 source, linear LDS dest).  X = f16 hi/lo
// of (-2x).  3-term MFMA (xh.eh + xh.el + xl.eh), split accumulators.
// C-init = (||e||^2+256)*2048; packed key ((uint)acc << 9) | idx -> u32-min
// argmin, first-min tie-break.  Near-ties (gap < 21/2048) -> exact f64.

typedef __attribute__((ext_vector_type(8))) _Float16 f16x8;
typedef __attribute__((ext_vector_type(4))) float f32x4;
typedef unsigned int uint;
typedef unsigned short ushort;

namespace {
constexpr int kC = 64, kH = 64, kW = 64;
constexpr int kK = 512, kD = 64;
constexpr int kHW = kH * kW;                  // 4096
constexpr int kCHW = kC * kHW;                // 262144
constexpr int kN = 32 * kHW;                  // 131072
constexpr int kQElems = 32 * kC * kHW;        // 8388608
constexpr uint kGapFP = 21u;                  // 0.0103 in 1/2048 units
}

__device__ __forceinline__ ushort hb(_Float16 h) { return __builtin_bit_cast(ushort, h); }
__device__ __forceinline__ uint umin(uint a, uint b) { return a < b ? a : b; }
__device__ __forceinline__ uint umax(uint a, uint b) { return a > b ? a : b; }

__device__ __forceinline__ void gld16(const void* g, void* l) {
  __builtin_amdgcn_global_load_lds(
      (const __attribute__((address_space(1))) uint*)g,
      (__attribute__((address_space(3))) uint*)l, 16, 0, 0);
}

// ---- kernel 0: E -> pre-swizzled f16 hi/lo (x2048) + enorm + zeros -----------
__global__ __launch_bounds__(64) void vq_prep(const float* __restrict__ emb,
                                              ushort* __restrict__ embPh,
                                              ushort* __restrict__ embPl,
                                              float* __restrict__ enorm,
                                              uint* __restrict__ counts,
                                              uint* __restrict__ flag_count) {
  const int k = blockIdx.x * 64 + threadIdx.x;
  const float4* __restrict__ ep4 = (const float4*)(emb + k * kD);
  uint uh[32], ul[32];
  float s = 0.f;
#pragma unroll
  for (int j = 0; j < kD / 4; ++j) {
    const float4 v = ep4[j];
    s = fmaf(v.x, v.x, s); s = fmaf(v.y, v.y, s);
    s = fmaf(v.z, v.z, s); s = fmaf(v.w, v.w, s);
    const float e0 = v.x * 2048.f, e1 = v.y * 2048.f;
    const float e2 = v.z * 2048.f, e3 = v.w * 2048.f;
    const _Float16 h0 = (_Float16)e0, h1 = (_Float16)e1;
    const _Float16 h2 = (_Float16)e2, h3 = (_Float16)e3;
    const _Float16 l0 = (_Float16)(e0 - (float)h0);
    const _Float16 l1 = (_Float16)(e1 - (float)h1);
    const _Float16 l2 = (_Float16)(e2 - (float)h2);
    const _Float16 l3 = (_Float16)(e3 - (float)h3);
    uh[2 * j] = (uint)hb(h0) | ((uint)hb(h1) << 16);
    uh[2 * j + 1] = (uint)hb(h2) | ((uint)hb(h3) << 16);
    ul[2 * j] = (uint)hb(l0) | ((uint)hb(l1) << 16);
    ul[2 * j + 1] = (uint)hb(l2) | ((uint)hb(l3) << 16);
  }
  // pre-swizzled store: embP[k*128B + (cc^(k&7))*16B] = linear chunk cc
  uint4* __restrict__ ph4 = (uint4*)embPh;
  uint4* __restrict__ pl4 = (uint4*)embPl;
#pragma unroll
  for (int cc = 0; cc < 8; ++cc) {
    const int dst = k * 8 + (cc ^ (k & 7));
    ph4[dst] = uint4{uh[4 * cc], uh[4 * cc + 1], uh[4 * cc + 2], uh[4 * cc + 3]};
    pl4[dst] = uint4{ul[4 * cc], ul[4 * cc + 1], ul[4 * cc + 2], ul[4 * cc + 3]};
  }
  enorm[k] = s;
  counts[k] = 0u;
  if (k == 0) *flag_count = 0u;
}

// ---- kernel 1: barrier-free MFMA argmin + flags + hist + loss + QW -----------
// Block 256 thr = 4 waves, 128 pts.  C/D: col=lane&15 (code),
// row=(lane>>4)*4+reg (point).
__global__ __launch_bounds__(256, 5) void vq_assign(
    const float* __restrict__ in, const float* __restrict__ emb,
    const ushort* __restrict__ embPh, const ushort* __restrict__ embPl,
    const float* __restrict__ enorm, float* __restrict__ idx_out,
    float* __restrict__ outq, uint* __restrict__ counts,
    float* __restrict__ partial, uint* __restrict__ flag_count,
    uint* __restrict__ flags, uint flag_cap) {
  __shared__ __align__(16) char lds[32768];
  // phase 1: X staging
  char* __restrict__ xbh = lds;                    // 16 KiB X hi (f16 of -2x)
  char* __restrict__ xbl = lds + 16384;            // 16 KiB X lo
  // phase 2 (after A-hoist): private dbuf, wave w at lds + w*8192:
  //   [buf0: hi 2048 | lo 2048][buf1: hi 2048 | lo 2048]
  // phase 3 (after loop): fidx[128] at lds[0,512), ldsE 16 KiB at lds+512
  uint* __restrict__ fidx = (uint*)lds;
  float* __restrict__ ldsE = (float*)(lds + 512);

  const int tid = threadIdx.x;
  const int lane = tid & 63;
  const int wv = __builtin_amdgcn_readfirstlane(tid >> 6);  // wave 0..3
  const int c = lane & 15;   // tile col (code)
  const int g = lane >> 4;   // k-chunk group 0..3

  const int blk = blockIdx.x;
  const int bb = blk >> 5;                  // batch
  const int hw0 = (blk & 31) << 7;          // 128 contiguous hw points
  const float* __restrict__ xp = in + (size_t)bb * kCHW + hw0;

  // ---- phase 1: stage X (hi/lo of -2x); wave wv = dims [wv*16..+16),
  // pts {lane, lane+64}; xnorm partial kept in-register.
  float xn = 0.f;
#pragma unroll
  for (int pp = 0; pp < 2; ++pp) {
    const int p = pp * 64 + lane;
    uint uh[8], ul[8];
#pragma unroll
    for (int j = 0; j < 8; ++j) {
      const float f0 = xp[(size_t)(wv * 16 + 2 * j) * kHW + p];
      const float f1 = xp[(size_t)(wv * 16 + 2 * j + 1) * kHW + p];
      xn = fmaf(f0, f0, xn);
      xn = fmaf(f1, f1, xn);
      const float m0 = -2.f * f0, m1f = -2.f * f1;
      const _Float16 h0 = (_Float16)m0, h1 = (_Float16)m1f;
      const _Float16 l0 = (_Float16)(m0 - (float)h0);
      const _Float16 l1 = (_Float16)(m1f - (float)h1);
      uh[j] = (uint)hb(h0) | ((uint)hb(h1) << 16);
      ul[j] = (uint)hb(l0) | ((uint)hb(l1) << 16);
    }
    const int swz = (p & 7) << 4;
    const int o0 = (p * 128 + wv * 32) ^ swz;
    const int o1 = (p * 128 + wv * 32 + 16) ^ swz;
    *(uint4*)(xbh + o0) = uint4{uh[0], uh[1], uh[2], uh[3]};
    *(uint4*)(xbh + o1) = uint4{uh[4], uh[5], uh[6], uh[7]};
    *(uint4*)(xbl + o0) = uint4{ul[0], ul[1], ul[2], ul[3]};
    *(uint4*)(xbl + o1) = uint4{ul[4], ul[5], ul[6], ul[7]};
  }
  // wave xnorm partial (dims [wv*16..+16) of all 128 pts)
  {
    float xw = xn;
#pragma unroll
    for (int off = 32; off > 0; off >>= 1) xw += __shfl_down(xw, off, 64);
    if (lane == 0) partial[blk * 8 + 4 + wv] = xw;
  }
  __syncthreads();   // X staged

  // ---- hoist A-fragments (hi+lo): 8 f16x8 = 32 VGPR ----
  f16x8 ah[2][2], al[2][2];
#pragma unroll
  for (int rt = 0; rt < 2; ++rt)
#pragma unroll
    for (int s = 0; s < 2; ++s) {
      const int row = wv * 32 + rt * 16 + c;
      const int off = (row * 128 + g * 16 + s * 64) ^ ((row & 7) << 4);
      ah[rt][s] = *(const f16x8*)(xbh + off);
      al[rt][s] = *(const f16x8*)(xbl + off);
    }

  // preload biased enorm for all 32 chunks (drained by the barrier below)
  float en_pre[32];
#pragma unroll
  for (int st = 0; st < 32; ++st)
    en_pre[st] = (enorm[st * 16 + c] + 256.f) * 2048.f;
  __syncthreads();   // X dead -> private dbuf region valid; vmcnt drained

  // ---- phase 2: barrier-free scan, 32 private 16-code chunks ----
  char* __restrict__ myE = lds + wv * 8192;
  auto stageE = [&](int buf, int st) {
    const size_t src = (size_t)st * 2048;
    char* d = myE + buf * 4096;
    gld16((const char*)embPh + src + lane * 16, d);
    gld16((const char*)embPh + src + 1024 + lane * 16, d + 1024);
    gld16((const char*)embPl + src + lane * 16, d + 2048);
    gld16((const char*)embPl + src + 1024 + lane * 16, d + 3072);
  };
  stageE(0, 0);

  uint m1[8], m2[8];
#pragma unroll
  for (int i = 0; i < 8; ++i) { m1[i] = 0xFFFFFFFFu; m2[i] = 0xFFFFFFFFu; }

#pragma unroll
  for (int st = 0; st < 32; ++st) {
    if (st < 31) stageE((st & 1) ^ 1, st + 1);   // prefetch stays in flight
    if (st < 31) {
      asm volatile("s_waitcnt vmcnt(4)" ::: "memory");   // my chunk-st landed
    } else {
      asm volatile("s_waitcnt vmcnt(0)" ::: "memory");
    }
    __builtin_amdgcn_sched_barrier(0);

    const char* bufp = myE + (st & 1) * 4096;
    const int swb = (c & 7) << 4;
    const int ob0 = (c * 128 + g * 16) ^ swb;
    const int ob1 = (c * 128 + g * 16 + 64) ^ swb;
    const f16x8 bh0 = *(const f16x8*)(bufp + ob0);
    const f16x8 bh1 = *(const f16x8*)(bufp + ob1);
    const f16x8 bl0 = *(const f16x8*)(bufp + 2048 + ob0);
    const f16x8 bl1 = *(const f16x8*)(bufp + 2048 + ob1);
    const float en = en_pre[st];
    const uint kor = (uint)(st * 16 + c);
#pragma unroll
    for (int rt = 0; rt < 2; ++rt) {
      // split accumulators: two independent 3-MFMA chains
      f32x4 acc0 = {en, en, en, en};
      f32x4 acc1 = {0.f, 0.f, 0.f, 0.f};
      acc0 = __builtin_amdgcn_mfma_f32_16x16x32_f16(ah[rt][0], bh0, acc0, 0, 0, 0);
      acc1 = __builtin_amdgcn_mfma_f32_16x16x32_f16(ah[rt][1], bh1, acc1, 0, 0, 0);
      acc0 = __builtin_amdgcn_mfma_f32_16x16x32_f16(ah[rt][0], bl0, acc0, 0, 0, 0);
      acc1 = __builtin_amdgcn_mfma_f32_16x16x32_f16(ah[rt][1], bl1, acc1, 0, 0, 0);
      acc0 = __builtin_amdgcn_mfma_f32_16x16x32_f16(al[rt][0], bh0, acc0, 0, 0, 0);
      acc1 = __builtin_amdgcn_mfma_f32_16x16x32_f16(al[rt][1], bh1, acc1, 0, 0, 0);
#pragma unroll
      for (int r = 0; r < 4; ++r) {
        const uint u = ((uint)(acc0[r] + acc1[r]) << 9) | kor;  // fixed-point
        const int i = rt * 4 + r;
        const uint t = umax(m1[i], u);
        m1[i] = umin(m1[i], u);
        m2[i] = umin(m2[i], t);
      }
    }
    // NO barrier: buffers are wave-private; program order + vmcnt suffice
  }

  // ---- cross-col butterfly (16 c-lanes per point); all in-wave ----
#pragma unroll
  for (int i = 0; i < 8; ++i) {
    uint a1 = m1[i], a2 = m2[i];
#pragma unroll
    for (int off = 1; off < 16; off <<= 1) {
      const uint o1 = __shfl_xor(a1, off, 64);
      const uint o2 = __shfl_xor(a2, off, 64);
      const uint t = umax(a1, o1);
      a1 = umin(a1, o1);
      a2 = umin(umin(a2, o2), t);
    }
    m1[i] = a1; m2[i] = a2;
  }
  __syncthreads();   // all waves done with dbuf -> phase-3 aliases valid

  // ---- c==0 lanes own 8 pts each: fidx/idx/flags/hist/loss ----
  float d2 = 0.f;
  if (c == 0) {
#pragma unroll
    for (int i = 0; i < 8; ++i) {
      const int rt = i >> 2, r = i & 3;
      const int p = wv * 32 + rt * 16 + g * 4 + r;
      const int n = blk * 128 + p;
      const uint bidx = m1[i] & 511u;
      fidx[p] = bidx;
      idx_out[n] = (float)bidx;
      if (((m2[i] >> 9) - (m1[i] >> 9)) < kGapFP) {   // near-tie -> recheck
        const uint slot = atomicAdd(flag_count, 1u);
        if (slot < flag_cap) flags[slot] = (uint)n;
      }
      atomicAdd(&counts[bidx], 1u);
      d2 += fmaf((float)(m1[i] >> 9), 1.f / 2048.f, -256.f);
    }
  }
#pragma unroll
  for (int off = 32; off > 0; off >>= 1) d2 += __shfl_down(d2, off, 64);
  if (lane == 0) partial[blk * 8 + wv] = d2;
  __syncthreads();   // fidx complete

  // ---- epilogue: two 64-row LDS-transpose half-passes ----
#pragma unroll
  for (int pp = 0; pp < 2; ++pp) {
#pragma unroll
    for (int pass2 = 0; pass2 < 4; ++pass2) {
      const int rr = pass2 * 16 + (tid >> 4);   // local row 0..63
      const int q = tid & 15;
      const float4 v = *(const float4*)(emb + fidx[pp * 64 + rr] * kD + q * 4);
      const int cswz = (q * 4) ^ (((rr >> 4) & 3) << 3);
      *(float4*)(ldsE + rr * 64 + cswz) = v;
    }
    __syncthreads();
    {
      const int ch = tid >> 2;          // channel 0..63
      const int wq = tid & 3;           // 16-pt chunk 0..3
      float* __restrict__ oq =
          outq + (size_t)bb * kCHW + (size_t)ch * kHW + hw0 + pp * 64 + wq * 16;
      float4 vv[4];
#pragma unroll
      for (int i = 0; i < 16; ++i) {
        const int p = wq * 16 + i;
        const int cswz = ch ^ (((p >> 4) & 3) << 3);
        ((float*)vv)[i] = ldsE[p * 64 + cswz];
      }
#pragma unroll
      for (int i = 0; i < 4; ++i) *(float4*)(oq + i * 4) = vv[i];
    }
    __syncthreads();   // ldsE reusable next half-pass
  }
}

// ---- kernel 1b: refine (blocks 0..255) + finalize (block 256), one dispatch --
__global__ __launch_bounds__(256) void vq_refine_fin(
    const float* __restrict__ in, const float* __restrict__ emb,
    const float* __restrict__ weight, const uint* __restrict__ flag_count,
    const uint* __restrict__ flags, uint flag_cap, float* __restrict__ idx_out,
    float* __restrict__ outq, const uint* __restrict__ counts,
    const float* __restrict__ partial, float* __restrict__ out_scalars) {
  if (blockIdx.x == 256) {
    // ---- finalize: fixed-order reductions (deterministic) ----
    __shared__ float red[256];
    const int t = threadIdx.x;

    {
      const float a0 = (float)counts[t] / (float)kN;
      const float a1 = (float)counts[t + 256] / (float)kN;
      red[t] = a0 * logf(a0 + 1e-10f) + a1 * logf(a1 + 1e-10f);
    }
    __syncthreads();
#pragma unroll
    for (int off = 128; off > 0; off >>= 1) {
      if (t < off) red[t] += red[t + off];
      __syncthreads();
    }
    const float perp = expf(-red[0]);
    __syncthreads();

    // loss: 8192 partials (1024 blocks x 8), fixed order
    {
      float a = 0.f;
#pragma unroll
      for (int j = 0; j < 32; ++j) a += partial[t + 256 * j];
      red[t] = a;
    }
    __syncthreads();
#pragma unroll
    for (int off = 128; off > 0; off >>= 1) {
      if (t < off) red[t] += red[t + off];
      __syncthreads();
    }
    const float loss = red[0] / (float)((long long)kN * (long long)kD);
    __syncthreads();

    red[t] = ((weight[t] >= 0.01f) ? 1.f : 0.f) +
             ((weight[t + 256] >= 0.01f) ? 1.f : 0.f);
    __syncthreads();
#pragma unroll
    for (int off = 128; off > 0; off >>= 1) {
      if (t < off) red[t] += red[t + off];
      __syncthreads();
    }
    if (t == 0) {
      out_scalars[0] = loss;
      out_scalars[1] = perp;
      out_scalars[2] = red[0];
    }
    return;
  }

  // ---- refine blocks: exact f64 re-argmin, ONE WAVE per flagged point ----
  uint cnt = *flag_count;
  if (cnt > flag_cap) cnt = flag_cap;
  const int lane = threadIdx.x & 63;
  const uint wave_id = blockIdx.x * 4u + (threadIdx.x >> 6);
  const uint wave_stride = 256u * 4u;

  for (uint i = wave_id; i < cnt; i += wave_stride) {
    const int n = (int)flags[i];          // wave-uniform
    const int b = n >> 12;
    const int hw = n & 4095;
    const float* __restrict__ xp = in + (size_t)b * kCHW + hw;

    float xr[kD];
#pragma unroll
    for (int d = 0; d < kD; ++d) xr[d] = xp[(size_t)d * kHW];

    double best = 1e300;
    int bidx = 0;
#pragma unroll 1
    for (int kk = 0; kk < 8; ++kk) {
      const int k = lane * 8 + kk;
      const float4* __restrict__ ep4 = (const float4*)(emb + k * kD);
      double s0 = 0.0, s1 = 0.0;
#pragma unroll
      for (int j = 0; j < kD / 4; ++j) {
        const float4 e = ep4[j];
        const double d0 = (double)xr[4 * j + 0] - (double)e.x;
        const double d1 = (double)xr[4 * j + 1] - (double)e.y;
        const double d2 = (double)xr[4 * j + 2] - (double)e.z;
        const double d3 = (double)xr[4 * j + 3] - (double)e.w;
        s0 = fma(d0, d0, s0);
        s1 = fma(d1, d1, s1);
        s0 = fma(d2, d2, s0);
        s1 = fma(d3, d3, s1);
      }
      const double s = s0 + s1;
      if (s < best) { best = s; bidx = k; }  // strict < == first-min in-lane
    }
#pragma unroll
    for (int off = 32; off > 0; off >>= 1) {
      const double ob = __shfl_xor(best, off, 64);
      const int oi = __shfl_xor(bidx, off, 64);
      if (ob < best || (ob == best && oi < bidx)) { best = ob; bidx = oi; }
    }
    if (lane == 0) idx_out[n] = (float)bidx;
    // patch quantized row: lane = channel
    outq[(size_t)b * kCHW + (size_t)lane * kHW + hw] = emb[bidx * kD + lane];
  }
}

extern "C" void kernel_launch(void* const* d_in, const int* in_sizes, int n_in,
                              void* d_out, int out_size, void* d_ws, size_t ws_size,
                              hipStream_t stream) {
  const float* in = (const float*)d_in[0];
  const float* emb = (const float*)d_in[1];
  const float* weight = (const float*)d_in[2];
  float* out = (float*)d_out;

  // workspace layout (4 B units)
  float* ws_f = (float*)d_ws;
  uint* ws_u = (uint*)d_ws;
  ushort* embPh = (ushort*)d_ws;            // 64 KiB  -> u32 [0, 16384)
  ushort* embPl = embPh + kK * kD;          // 64 KiB  -> u32 [16384, 32768)
  float* enorm = ws_f + 65536;              // [512]
  uint* counts = ws_u + 66048;              // [512]
  float* partial = ws_f + 66560;            // [8192]
  uint* flag_count = ws_u + 74752;          // [1]
  uint* flags = ws_u + 74753;               // [flag_cap]
  const size_t ws_elems = ws_size / 4;
  const uint flag_cap =
      (ws_elems > 74753)
          ? (uint)((ws_elems - 74753 < (size_t)kN) ? ws_elems - 74753 : (size_t)kN)
          : 0u;

  float* outq = out;                    // [8388608]
  float* out_scalars = out + kQElems;   // [3]
  float* idx_out = out + kQElems + 3;   // [131072]

  vq_prep<<<8, 64, 0, stream>>>(emb, embPh, embPl, enorm, counts, flag_count);
  vq_assign<<<kN / 128, 256, 0, stream>>>(in, emb, embPh, embPl, enorm, idx_out,
                                          outq, counts, partial, flag_count, flags,
                                          flag_cap);
  vq_refine_fin<<<257, 256, 0, stream>>>(in, emb, weight, flag_count, flags,
                                         flag_cap, idx_out, outq, counts, partial,
                                         out_scalars);
}

// Round 23
// 84.221 us; speedup vs baseline: 2.5165x; 2.5165x over previous
//
#include <hip/hip_runtime.h>

// VectorQuantizer on MI355X (gfx950) — async-pipelined MFMA argmin (counted
// vmcnt, raw s_barrier) + LDS-transpose fused quantized write; f64 refine
// patches near-ties.  R23 = r21 verbatim (best measured: 83.98 us) — the
// r22 barrier-free/private-dbuf experiment regressed (en_pre[32] spilled to
// scratch at VGPR=48; 4x E-traffic), closing the structural hypothesis list.
// This configuration is the session's practical floor.
//
// Distance core: s = ||e||^2 - 2 x.e.  E pre-scaled by 2048, f16 hi/lo split,
// PRE-SWIZZLED in ws (per-lane gld16 source, linear LDS dest).  X = f16 hi/lo
// of (-2x).  3-term MFMA (xh.eh + xh.el + xl.eh), split accumulators.
// C-init = (||e||^2+256)*2048; packed key ((uint)acc << 9) | idx -> u32-min
// argmin, first-min tie-break.  Near-ties (gap < 21/2048) re-solved in f64 by
// vq_refine (patches idx AND quantized rows).  Loss/hist pre-refine.

typedef __attribute__((ext_vector_type(8))) _Float16 f16x8;
typedef __attribute__((ext_vector_type(4))) float f32x4;
typedef unsigned int uint;
typedef unsigned short ushort;

namespace {
constexpr int kC = 64, kH = 64, kW = 64;
constexpr int kK = 512, kD = 64;
constexpr int kHW = kH * kW;                  // 4096
constexpr int kCHW = kC * kHW;                // 262144
constexpr int kN = 32 * kHW;                  // 131072
constexpr int kQElems = 32 * kC * kHW;        // 8388608
constexpr uint kGapFP = 21u;                  // 0.0103 in 1/2048 units
}

__device__ __forceinline__ ushort hb(_Float16 h) { return __builtin_bit_cast(ushort, h); }
__device__ __forceinline__ uint umin(uint a, uint b) { return a < b ? a : b; }
__device__ __forceinline__ uint umax(uint a, uint b) { return a > b ? a : b; }

__device__ __forceinline__ void gld16(const void* g, void* l) {
  __builtin_amdgcn_global_load_lds(
      (const __attribute__((address_space(1))) uint*)g,
      (__attribute__((address_space(3))) uint*)l, 16, 0, 0);
}

// ---- kernel 0: E -> pre-swizzled f16 hi/lo (x2048) + enorm + zeros -----------
__global__ __launch_bounds__(64) void vq_prep(const float* __restrict__ emb,
                                              ushort* __restrict__ embPh,
                                              ushort* __restrict__ embPl,
                                              float* __restrict__ enorm,
                                              uint* __restrict__ counts,
                                              uint* __restrict__ flag_count) {
  const int k = blockIdx.x * 64 + threadIdx.x;
  const float4* __restrict__ ep4 = (const float4*)(emb + k * kD);
  uint uh[32], ul[32];
  float s = 0.f;
#pragma unroll
  for (int j = 0; j < kD / 4; ++j) {
    const float4 v = ep4[j];
    s = fmaf(v.x, v.x, s); s = fmaf(v.y, v.y, s);
    s = fmaf(v.z, v.z, s); s = fmaf(v.w, v.w, s);
    const float e0 = v.x * 2048.f, e1 = v.y * 2048.f;
    const float e2 = v.z * 2048.f, e3 = v.w * 2048.f;
    const _Float16 h0 = (_Float16)e0, h1 = (_Float16)e1;
    const _Float16 h2 = (_Float16)e2, h3 = (_Float16)e3;
    const _Float16 l0 = (_Float16)(e0 - (float)h0);
    const _Float16 l1 = (_Float16)(e1 - (float)h1);
    const _Float16 l2 = (_Float16)(e2 - (float)h2);
    const _Float16 l3 = (_Float16)(e3 - (float)h3);
    uh[2 * j] = (uint)hb(h0) | ((uint)hb(h1) << 16);
    uh[2 * j + 1] = (uint)hb(h2) | ((uint)hb(h3) << 16);
    ul[2 * j] = (uint)hb(l0) | ((uint)hb(l1) << 16);
    ul[2 * j + 1] = (uint)hb(l2) | ((uint)hb(l3) << 16);
  }
  // pre-swizzled store: embP[k*128B + (cc^(k&7))*16B] = linear chunk cc
  uint4* __restrict__ ph4 = (uint4*)embPh;
  uint4* __restrict__ pl4 = (uint4*)embPl;
#pragma unroll
  for (int cc = 0; cc < 8; ++cc) {
    const int dst = k * 8 + (cc ^ (k & 7));
    ph4[dst] = uint4{uh[4 * cc], uh[4 * cc + 1], uh[4 * cc + 2], uh[4 * cc + 3]};
    pl4[dst] = uint4{ul[4 * cc], ul[4 * cc + 1], ul[4 * cc + 2], ul[4 * cc + 3]};
  }
  enorm[k] = s;
  counts[k] = 0u;
  if (k == 0) *flag_count = 0u;
}

// ---- kernel 1: MFMA argmin + flags + hist + loss + QUANTIZED WRITE -----------
// Block = 512 thr = 8 waves = 128 points x all 512 codes in 8 dbuf-staged
// 64-code chunks.  Wave (ph=wv>>2, cs=wv&3).  Wave stages ITS OWN 16 rows.
// C/D: col=lane&15 (code), row=(lane>>4)*4+reg (point).
__global__ __launch_bounds__(512, 4) void vq_assign(
    const float* __restrict__ in, const float* __restrict__ emb,
    const ushort* __restrict__ embPh, const ushort* __restrict__ embPl,
    const float* __restrict__ enorm, float* __restrict__ idx_out,
    float* __restrict__ outq, uint* __restrict__ counts,
    float* __restrict__ partial, uint* __restrict__ flag_count,
    uint* __restrict__ flags, uint flag_cap) {
  __shared__ __align__(16) char lds[74240];
  char* __restrict__ xbh = lds;                     // 16 KiB X hi (f16 of -2x)
  char* __restrict__ xbl = lds + 16384;             // 16 KiB X lo
  char* __restrict__ ebh = lds + 32768;             // [2][8192 B] E hi dbuf
  char* __restrict__ ebl = lds + 49152;             // [2][8192 B] E lo dbuf
  uint* __restrict__ mm1 = (uint*)(lds + 65536);    // [4][128]
  uint* __restrict__ mm2 = (uint*)(lds + 67584);    // [4][128]
  float* __restrict__ xnp = (float*)(lds + 69632);  // [4][128]
  uint* __restrict__ hist = (uint*)(lds + 71680);   // [512]
  uint* __restrict__ fidx = (uint*)(lds + 73728);   // [128]
  float* __restrict__ ldsE = (float*)lds;           // epilogue alias (32 KiB,
                                                    // over dead xbh/xbl only)

  const int tid = threadIdx.x;
  const int lane = tid & 63;
  const int wv = __builtin_amdgcn_readfirstlane(tid >> 6);
  const int ph = wv >> 2;    // point-half
  const int cs = wv & 3;     // code-sub (16 codes per 64-code chunk)
  const int c = lane & 15;   // tile col (code)
  const int g = lane >> 4;   // k-chunk group 0..3

  const int blk = blockIdx.x;
  const int bb = blk >> 5;                  // batch
  const int hw0 = (blk & 31) << 7;          // 128 contiguous hw points
  const float* __restrict__ xp = in + (size_t)bb * kCHW + hw0 + ph * 64;

  hist[tid] = 0u;

  // SELF-STAGE: wave (ph,cs) stages rows [cs*16, cs*16+16) of chunk st —
  // exactly the rows it reads.  ph-siblings duplicate identical bytes (benign).
  auto stageE = [&](int buf, int st) {
    const size_t src = (size_t)st * 8192 + cs * 2048;
    const int dst = buf * 8192 + cs * 2048;
#pragma unroll
    for (int i = 0; i < 2; ++i) {
      gld16((const char*)embPh + src + i * 1024 + lane * 16, ebh + dst + i * 1024);
      gld16((const char*)embPl + src + i * 1024 + lane * 16, ebl + dst + i * 1024);
    }
  };
  stageE(0, 0);   // prologue prefetch, flies under X staging

  // scaled+biased C-init per lane for the 8 chunks
  float en_pre[8];
#pragma unroll
  for (int st = 0; st < 8; ++st)
    en_pre[st] = (enorm[st * 64 + cs * 16 + c] + 256.f) * 2048.f;

  // ---- stage X (hi/lo of -2x) + xnorm partial over this wave's 16 dims ----
  {
    const int p = lane;
    uint uh[8], ul[8];
    float xn = 0.f;
#pragma unroll
    for (int j = 0; j < 8; ++j) {
      const float f0 = xp[(size_t)(cs * 16 + 2 * j) * kHW + p];
      const float f1 = xp[(size_t)(cs * 16 + 2 * j + 1) * kHW + p];
      xn = fmaf(f0, f0, xn);
      xn = fmaf(f1, f1, xn);
      const float m0 = -2.f * f0, m1f = -2.f * f1;
      const _Float16 h0 = (_Float16)m0, h1 = (_Float16)m1f;
      const _Float16 l0 = (_Float16)(m0 - (float)h0);
      const _Float16 l1 = (_Float16)(m1f - (float)h1);
      uh[j] = (uint)hb(h0) | ((uint)hb(h1) << 16);
      ul[j] = (uint)hb(l0) | ((uint)hb(l1) << 16);
    }
    const int row = ph * 64 + p;
    const int swz = (row & 7) << 4;
    const int o0 = (row * 128 + cs * 32) ^ swz;
    const int o1 = (row * 128 + cs * 32 + 16) ^ swz;
    *(uint4*)(xbh + o0) = uint4{uh[0], uh[1], uh[2], uh[3]};
    *(uint4*)(xbh + o1) = uint4{uh[4], uh[5], uh[6], uh[7]};
    *(uint4*)(xbl + o0) = uint4{ul[0], ul[1], ul[2], ul[3]};
    *(uint4*)(xbl + o1) = uint4{ul[4], ul[5], ul[6], ul[7]};
    xnp[cs * 128 + row] = xn;
  }
  __syncthreads();   // full drain ONCE: X staged + chunk 0 landed

  uint m1[16], m2[16];
#pragma unroll
  for (int i = 0; i < 16; ++i) { m1[i] = 0xFFFFFFFFu; m2[i] = 0xFFFFFFFFu; }

#pragma unroll
  for (int st = 0; st < 8; ++st) {
    if (st < 7) stageE((st & 1) ^ 1, st + 1);   // prefetch stays in flight

    // counted wait: my own chunk-st loads landed (4 newest = chunk st+1)
    if (st < 7) {
      asm volatile("s_waitcnt vmcnt(4)" ::: "memory");
    } else {
      asm volatile("s_waitcnt vmcnt(0)" ::: "memory");
    }
    __builtin_amdgcn_sched_barrier(0);

    // B-frags: this wave's 16-code slice of the chunk (self-staged)
    const int rowb = cs * 16 + c;
    const int swb = (rowb & 7) << 4;
    const int bbase = (st & 1) * 8192;
    const int ob0 = bbase + ((rowb * 128 + g * 16) ^ swb);
    const int ob1 = bbase + ((rowb * 128 + g * 16 + 64) ^ swb);
    const f16x8 bh0 = *(const f16x8*)(ebh + ob0);
    const f16x8 bh1 = *(const f16x8*)(ebh + ob1);
    const f16x8 bl0 = *(const f16x8*)(ebl + ob0);
    const f16x8 bl1 = *(const f16x8*)(ebl + ob1);
    const float en = en_pre[st];
    const uint kor = (uint)(st * 64 + cs * 16 + c);
    __builtin_amdgcn_s_setprio(1);
#pragma unroll
    for (int rt = 0; rt < 4; ++rt) {
      f16x8 ah[2], al[2];
#pragma unroll
      for (int s = 0; s < 2; ++s) {
        const int row = ph * 64 + rt * 16 + c;
        const int off = (row * 128 + g * 16 + s * 64) ^ ((row & 7) << 4);
        ah[s] = *(const f16x8*)(xbh + off);
        al[s] = *(const f16x8*)(xbl + off);
      }
      // split accumulators: two independent 3-MFMA chains
      f32x4 acc0 = {en, en, en, en};
      f32x4 acc1 = {0.f, 0.f, 0.f, 0.f};
      acc0 = __builtin_amdgcn_mfma_f32_16x16x32_f16(ah[0], bh0, acc0, 0, 0, 0);
      acc1 = __builtin_amdgcn_mfma_f32_16x16x32_f16(ah[1], bh1, acc1, 0, 0, 0);
      acc0 = __builtin_amdgcn_mfma_f32_16x16x32_f16(ah[0], bl0, acc0, 0, 0, 0);
      acc1 = __builtin_amdgcn_mfma_f32_16x16x32_f16(ah[1], bl1, acc1, 0, 0, 0);
      acc0 = __builtin_amdgcn_mfma_f32_16x16x32_f16(al[0], bh0, acc0, 0, 0, 0);
      acc1 = __builtin_amdgcn_mfma_f32_16x16x32_f16(al[1], bh1, acc1, 0, 0, 0);
#pragma unroll
      for (int r = 0; r < 4; ++r) {
        const uint u = ((uint)(acc0[r] + acc1[r]) << 9) | kor;  // fixed-point
        const int i = rt * 4 + r;
        const uint t = umax(m1[i], u);
        m1[i] = umin(m1[i], u);
        m2[i] = umin(m2[i], t);
      }
    }
    __builtin_amdgcn_s_setprio(0);

    // step-end rendezvous WITHOUT vmcnt drain (prefetch stays in flight)
    asm volatile("s_waitcnt lgkmcnt(0)" ::: "memory");
    __builtin_amdgcn_sched_barrier(0);
    __builtin_amdgcn_s_barrier();
  }

  // ---- cross-col butterfly (16 c-lanes per point) ----
#pragma unroll
  for (int i = 0; i < 16; ++i) {
    uint a1 = m1[i], a2 = m2[i];
#pragma unroll
    for (int off = 1; off < 16; off <<= 1) {
      const uint o1 = __shfl_xor(a1, off, 64);
      const uint o2 = __shfl_xor(a2, off, 64);
      const uint t = umax(a1, o1);
      a1 = umin(a1, o1);
      a2 = umin(umin(a2, o2), t);
    }
    m1[i] = a1; m2[i] = a2;
  }

  if (c == 0) {
#pragma unroll
    for (int i = 0; i < 16; ++i) {
      const int p = ph * 64 + (i >> 2) * 16 + g * 4 + (i & 3);
      mm1[cs * 128 + p] = m1[i];
      mm2[cs * 128 + p] = m2[i];
    }
  }
  __syncthreads();

  // ---- cross-wave merge + idx/flags/hist/loss ----
  if (tid < 128) {
    uint a1 = mm1[tid], a2 = mm2[tid];
#pragma unroll
    for (int s = 1; s < 4; ++s) {
      const uint u1 = mm1[s * 128 + tid], u2 = mm2[s * 128 + tid];
      const uint t = umax(a1, u1);
      a1 = umin(a1, u1);
      a2 = umin(umin(a2, u2), t);
    }
    const uint bidx = a1 & 511u;
    fidx[tid] = bidx;
    idx_out[blk * 128 + tid] = (float)bidx;
    if (((a2 >> 9) - (a1 >> 9)) < kGapFP) {   // near-tie -> exact recheck
      const uint slot = atomicAdd(flag_count, 1u);
      if (slot < flag_cap) flags[slot] = (uint)(blk * 128 + tid);
    }
    atomicAdd(&hist[bidx], 1u);

    const float xnorm = (xnp[tid] + xnp[128 + tid]) + (xnp[256 + tid] + xnp[384 + tid]);
    float d2 = fmaf((float)(a1 >> 9), 1.f / 2048.f, -256.f) + xnorm;
#pragma unroll
    for (int off = 32; off > 0; off >>= 1) d2 += __shfl_down(d2, off, 64);
    if ((tid & 63) == 0) partial[blk * 2 + (tid >> 6)] = d2;
  }
  __syncthreads();   // fidx + hist complete; X region (xbh/xbl) now dead
  if (hist[tid]) atomicAdd(&counts[tid], hist[tid]);

  // ---- LDS-transpose epilogue: stage the 128 selected e-rows (coalesced
  // 256 B row fetches) into XOR-swizzled ldsE, then NCHW-coalesced stores.
#pragma unroll
  for (int pass = 0; pass < 4; ++pass) {
    const int r = pass * 32 + (tid >> 4);   // point 0..127
    const int q = tid & 15;                 // float4 quad within the row
    const float4 v = *(const float4*)(emb + fidx[r] * kD + q * 4);
    const int cswz = (q * 4) ^ (((r >> 4) & 7) << 3);
    *(float4*)(ldsE + r * 64 + cswz) = v;
  }
  __syncthreads();
  {
    const int ch = tid >> 3;          // channel 0..63
    const int wq = tid & 7;           // 16-pt chunk 0..7
    float* __restrict__ oq = outq + (size_t)bb * kCHW + (size_t)ch * kHW + hw0 + wq * 16;
    float4 vv[4];
#pragma unroll
    for (int i = 0; i < 16; ++i) {
      const int p = wq * 16 + i;
      const int cswz = ch ^ (((p >> 4) & 7) << 3);
      ((float*)vv)[i] = ldsE[p * 64 + cswz];
    }
#pragma unroll
    for (int i = 0; i < 4; ++i) *(float4*)(oq + i * 4) = vv[i];
  }
}

// ---- kernel 1b: refine (blocks 0..255) + finalize (block 256), one dispatch --
// Refine: exact f64 re-argmin, ONE WAVE per flagged point; patches idx_out and
// the quantized row.  Finalize: loss/perplexity/usage from assign's outputs
// (independent of refine -> runs concurrently).
__global__ __launch_bounds__(256) void vq_refine_fin(
    const float* __restrict__ in, const float* __restrict__ emb,
    const float* __restrict__ weight, const uint* __restrict__ flag_count,
    const uint* __restrict__ flags, uint flag_cap, float* __restrict__ idx_out,
    float* __restrict__ outq, const uint* __restrict__ counts,
    const float* __restrict__ partial, float* __restrict__ out_scalars) {
  if (blockIdx.x == 256) {
    // ---- finalize: 256 threads, fixed-order reductions (deterministic) ----
    __shared__ float red[256];
    const int t = threadIdx.x;

    // perplexity = exp(-sum(avg * log(avg + 1e-10)))
    {
      const float a0 = (float)counts[t] / (float)kN;
      const float a1 = (float)counts[t + 256] / (float)kN;
      red[t] = a0 * logf(a0 + 1e-10f) + a1 * logf(a1 + 1e-10f);
    }
    __syncthreads();
#pragma unroll
    for (int off = 128; off > 0; off >>= 1) {
      if (t < off) red[t] += red[t + off];
      __syncthreads();
    }
    const float perp = expf(-red[0]);
    __syncthreads();

    // loss: 2048 partials, fixed order
    {
      float a = 0.f;
#pragma unroll
      for (int j = 0; j < 8; ++j) a += partial[t + 256 * j];
      red[t] = a;
    }
    __syncthreads();
#pragma unroll
    for (int off = 128; off > 0; off >>= 1) {
      if (t < off) red[t] += red[t + off];
      __syncthreads();
    }
    const float loss = red[0] / (float)((long long)kN * (long long)kD);
    __syncthreads();

    // usage = sum(weight >= 0.01)
    red[t] = ((weight[t] >= 0.01f) ? 1.f : 0.f) +
             ((weight[t + 256] >= 0.01f) ? 1.f : 0.f);
    __syncthreads();
#pragma unroll
    for (int off = 128; off > 0; off >>= 1) {
      if (t < off) red[t] += red[t + off];
      __syncthreads();
    }
    if (t == 0) {
      out_scalars[0] = loss;
      out_scalars[1] = perp;
      out_scalars[2] = red[0];
    }
    return;
  }

  // ---- refine blocks ----
  uint cnt = *flag_count;
  if (cnt > flag_cap) cnt = flag_cap;
  const int lane = threadIdx.x & 63;
  const uint wave_id = blockIdx.x * 4u + (threadIdx.x >> 6);
  const uint wave_stride = 256u * 4u;

  for (uint i = wave_id; i < cnt; i += wave_stride) {
    const int n = (int)flags[i];          // wave-uniform
    const int b = n >> 12;
    const int hw = n & 4095;
    const float* __restrict__ xp = in + (size_t)b * kCHW + hw;

    float xr[kD];
#pragma unroll
    for (int d = 0; d < kD; ++d) xr[d] = xp[(size_t)d * kHW];

    double best = 1e300;
    int bidx = 0;
#pragma unroll 1
    for (int kk = 0; kk < 8; ++kk) {
      const int k = lane * 8 + kk;
      const float4* __restrict__ ep4 = (const float4*)(emb + k * kD);
      double s0 = 0.0, s1 = 0.0;
#pragma unroll
      for (int j = 0; j < kD / 4; ++j) {
        const float4 e = ep4[j];
        const double d0 = (double)xr[4 * j + 0] - (double)e.x;
        const double d1 = (double)xr[4 * j + 1] - (double)e.y;
        const double d2 = (double)xr[4 * j + 2] - (double)e.z;
        const double d3 = (double)xr[4 * j + 3] - (double)e.w;
        s0 = fma(d0, d0, s0);
        s1 = fma(d1, d1, s1);
        s0 = fma(d2, d2, s0);
        s1 = fma(d3, d3, s1);
      }
      const double s = s0 + s1;
      if (s < best) { best = s; bidx = k; }  // strict < == first-min in-lane
    }
#pragma unroll
    for (int off = 32; off > 0; off >>= 1) {
      const double ob = __shfl_xor(best, off, 64);
      const int oi = __shfl_xor(bidx, off, 64);
      if (ob < best || (ob == best && oi < bidx)) { best = ob; bidx = oi; }
    }
    if (lane == 0) idx_out[n] = (float)bidx;
    // patch quantized row: lane = channel
    outq[(size_t)b * kCHW + (size_t)lane * kHW + hw] = emb[bidx * kD + lane];
  }
}

extern "C" void kernel_launch(void* const* d_in, const int* in_sizes, int n_in,
                              void* d_out, int out_size, void* d_ws, size_t ws_size,
                              hipStream_t stream) {
  const float* in = (const float*)d_in[0];
  const float* emb = (const float*)d_in[1];
  const float* weight = (const float*)d_in[2];
  float* out = (float*)d_out;

  // workspace layout (4 B units)
  float* ws_f = (float*)d_ws;
  uint* ws_u = (uint*)d_ws;
  ushort* embPh = (ushort*)d_ws;            // 64 KiB  -> u32 [0, 16384)
  ushort* embPl = embPh + kK * kD;          // 64 KiB  -> u32 [16384, 32768)
  float* enorm = ws_f + 65536;              // [512]
  uint* counts = ws_u + 66048;              // [512]
  float* partial = ws_f + 66560;            // [2048]
  uint* flag_count = ws_u + 68608;          // [1]
  uint* flags = ws_u + 68609;               // [flag_cap]
  const size_t ws_elems = ws_size / 4;
  const uint flag_cap =
      (ws_elems > 68609)
          ? (uint)((ws_elems - 68609 < (size_t)kN) ? ws_elems - 68609 : (size_t)kN)
          : 0u;

  float* outq = out;                    // [8388608]
  float* out_scalars = out + kQElems;   // [3]
  float* idx_out = out + kQElems + 3;   // [131072]

  vq_prep<<<8, 64, 0, stream>>>(emb, embPh, embPl, enorm, counts, flag_count);
  vq_assign<<<kN / 128, 512, 0, stream>>>(in, emb, embPh, embPl, enorm, idx_out,
                                          outq, counts, partial, flag_count, flags,
                                          flag_cap);
  vq_refine_fin<<<257, 256, 0, stream>>>(in, emb, weight, flag_count, flags,
                                         flag_cap, idx_out, outq, counts, partial,
                                         out_scalars);
}